// Round 1
// baseline (6899.708 us; speedup 1.0000x reference)
//
#include <hip/hip_runtime.h>
#include <hip/hip_bf16.h>
#include <math.h>

// ---------------- problem constants ----------------
#define N_IMG 64
#define H_IN  256
#define W_IN  256
#define CH    64      // PCN_H
#define HP1   128     // spatial after pool1
#define WP1   128
#define HP2   64      // spatial after pool2
#define WP2   64
#define F1_PW 136     // feat1 padded width: col x in [-4,131] stored at x+4

// d_out layout (floats):
//   feature_map (8,64,8,64,64)  : [0, 16777216)
//   counts      (8,1,8,64,64)   : [16777216, 17039360)
//   rgb_map     (8,3,8,64,64)   : [17039360, 17825792)
#define OUT_CNT_BASE 16777216
#define OUT_RGB_BASE 17039360

#define FEAT1_BYTES ((size_t)N_IMG * CH * HP1 * F1_PW * 2)

// mish(x) = x * tanh(softplus(x)) = x * (t^2+2t)/(t^2+2t+2), t=e^x
__device__ __forceinline__ float fast_mish(float x) {
    float xc = fminf(x, 20.0f);
    float t  = __expf(xc);
    float n  = t * (t + 2.0f);
    float y  = x * n / (n + 2.0f);
    return (x > 20.0f) ? x : y;
}

// ------------- kernel 1: per-point binning + rgb/count scatter -------------
__global__ __launch_bounds__(256) void point_kernel(
    const float* __restrict__ rgb,
    const float* __restrict__ sxyz,
    const int*   __restrict__ index,
    float*       __restrict__ out,
    int*         __restrict__ lin_pt)
{
    int p = blockIdx.x * 256 + threadIdx.x;      // 64*64*64 = 262144 points
    int n  = p >> 12;
    int r  = p & 4095;
    int hs = r >> 6;
    int ws = r & 63;

    int row = hs * 4 + 2, col = ws * 4 + 2;
    const float* sx = sxyz + (size_t)n * 3 * 65536;
    float X = sx[row * 256 + col];
    float Y = sx[65536 + row * 256 + col];
    float Z = sx[2 * 65536 + row * 256 + col];

    // replicate JAX op order + trunc-toward-zero int cast
    int hb = (int)(((X + 5.0f) * 64.0f) / 10.0f);
    int wb = (int)(((Y + 5.0f) * 64.0f) / 10.0f);
    int vb = (int)((Z * 8.0f) / 3.0f);
    bool valid = (hb >= 0) & (hb < 64) & (wb >= 0) & (wb < 64) & (vb >= 0) & (vb < 8);

    int b   = index[n];
    int lin = ((b * 8 + vb) * 64 + hb) * 64 + wb;   // b*32768 + vb*4096 + hb*64 + wb
    lin_pt[p] = valid ? lin : -1;

    if (valid) {
        atomicAdd(out + OUT_CNT_BASE + lin, 1.0f);
        int rem = lin & 32767;
        #pragma unroll
        for (int c = 0; c < 3; c++) {
            const float* rg = rgb + (size_t)(n * 3 + c) * 65536;
            float s = 0.0f;
            #pragma unroll
            for (int i = 0; i < 4; i++)
                #pragma unroll
                for (int j = 0; j < 4; j++)
                    s += rg[(hs * 4 + i) * 256 + (ws * 4 + j)];
            atomicAdd(out + OUT_RGB_BASE + b * 98304 + c * 32768 + rem, s * 0.0625f);
        }
    }
}

// ------------- kernel 2: conv1(3->64, dil2) + mish + maxpool3s2 -> feat1 bf16 -------------
__global__ __launch_bounds__(256) void conv1_kernel(
    const float* __restrict__ rgb,
    const float* __restrict__ w1,
    __hip_bfloat16* __restrict__ feat1)
{
    int id = blockIdx.x * 256 + threadIdx.x;   // ((n*64+co)*128+ho)*128+wo
    int wo = id & 127;
    int ho = (id >> 7) & 127;
    int co = (id >> 14) & 63;
    int n  = id >> 20;

    float c[3][3] = {{0.f,0.f,0.f},{0.f,0.f,0.f},{0.f,0.f,0.f}};

    for (int ci = 0; ci < 3; ci++) {
        const float* img = rgb + (size_t)(n * 3 + ci) * 65536;
        const float* wsr = w1 + (co * 3 + ci) * 9;
        float wreg[9];
        #pragma unroll
        for (int t = 0; t < 9; t++) wreg[t] = wsr[t];

        #pragma unroll
        for (int dr = -3; dr <= 3; dr++) {
            int rr = 2 * ho + dr;
            float v[8];
            if (rr >= 0 && rr < 256) {
                const float* rp = img + rr * 256;
                #pragma unroll
                for (int j = 0; j < 8; j++) {
                    int x = 2 * wo - 4 + j;
                    v[j] = (x >= 0 && x < 256) ? rp[x] : 0.0f;
                }
            } else {
                #pragma unroll
                for (int j = 0; j < 8; j++) v[j] = 0.0f;
            }
            // input row rr feeds conv row y=2ho-1+py when 2(ky-1) = dr-(py-1)
            #pragma unroll
            for (int py = 0; py < 3; py++) {
                int kyo = dr - (py - 1);
                if (kyo == -2 || kyo == 0 || kyo == 2) {
                    int ky = kyo / 2 + 1;
                    #pragma unroll
                    for (int px = 0; px < 3; px++)
                        #pragma unroll
                        for (int kx = 0; kx < 3; kx++)
                            c[py][px] += wreg[ky * 3 + kx] * v[(px - 1) + 2 * (kx - 1) + 4];
                }
            }
        }
    }

    float m = -INFINITY;
    #pragma unroll
    for (int py = 0; py < 3; py++) {
        int y = 2 * ho - 1 + py;
        if (y < 0 || y >= 256) continue;
        #pragma unroll
        for (int px = 0; px < 3; px++) {
            int x = 2 * wo - 1 + px;
            if (x < 0 || x >= 256) continue;
            m = fmaxf(m, fast_mish(c[py][px]));
        }
    }
    feat1[((size_t)(n * 64 + co) * HP1 + ho) * F1_PW + (wo + 4)] = __float2bfloat16(m);
}

// ------------- kernel 3: conv2(64->64, dil2) + mish + maxpool3s2 + feature scatter -------------
__global__ __launch_bounds__(256) void conv2_kernel(
    const __hip_bfloat16* __restrict__ feat1,
    const float* __restrict__ w2,
    const int*   __restrict__ lin_pt,
    float*       __restrict__ out)
{
    // grid: ((n*4 + cg)*64 + ho); block: 4 waves x 64 lanes(wo); thread: 4 co
    int bid  = blockIdx.x;
    int ho   = bid & 63;
    int cg   = (bid >> 6) & 3;
    int n    = bid >> 8;
    int wo   = threadIdx.x & 63;
    int wave = threadIdx.x >> 6;

    __shared__ float wl[16 * 64 * 9];   // 16 co x 64 ci x 9 taps = 36 KB
    {
        const float* wsrc = w2 + cg * 16 * 576;   // co block contiguous
        for (int i = threadIdx.x; i < 9216; i += 256) wl[i] = wsrc[i];
    }
    __syncthreads();

    float acc[4][3][3];
    #pragma unroll
    for (int k = 0; k < 4; k++)
        #pragma unroll
        for (int a = 0; a < 3; a++)
            #pragma unroll
            for (int bq = 0; bq < 3; bq++) acc[k][a][bq] = 0.0f;

    const __hip_bfloat16* f1n = feat1 + (size_t)n * CH * HP1 * F1_PW;

    for (int ci = 0; ci < 64; ci++) {
        // hoist this ci's 4x9 weights to registers
        float wr[4][9];
        #pragma unroll
        for (int k = 0; k < 4; k++)
            #pragma unroll
            for (int t = 0; t < 9; t++)
                wr[k][t] = wl[((wave * 4 + k) * 64 + ci) * 9 + t];

        const __hip_bfloat16* fp = f1n + (size_t)ci * HP1 * F1_PW;
        #pragma unroll
        for (int dr = -3; dr <= 3; dr++) {
            int rr = 2 * ho + dr;
            float v[8];
            if (rr >= 0 && rr < 128) {
                const unsigned int* rp32 =
                    reinterpret_cast<const unsigned int*>(fp + rr * F1_PW + 2 * wo); // x=2wo-4 stored at col 2wo
                #pragma unroll
                for (int k = 0; k < 4; k++) {
                    unsigned int u = rp32[k];
                    v[2 * k]     = __uint_as_float(u << 16);
                    v[2 * k + 1] = __uint_as_float(u & 0xFFFF0000u);
                }
            } else {
                #pragma unroll
                for (int j = 0; j < 8; j++) v[j] = 0.0f;
            }
            #pragma unroll
            for (int py = 0; py < 3; py++) {
                int kyo = dr - (py - 1);
                if (kyo == -2 || kyo == 0 || kyo == 2) {
                    int ky = kyo / 2 + 1;
                    #pragma unroll
                    for (int k = 0; k < 4; k++)
                        #pragma unroll
                        for (int px = 0; px < 3; px++)
                            #pragma unroll
                            for (int kx = 0; kx < 3; kx++)
                                acc[k][py][px] += wr[k][ky * 3 + kx] * v[(px - 1) + 2 * (kx - 1) + 4];
                }
            }
        }
    }

    // mish + 3x3 s2 maxpool (pooled coord = (ho,wo))
    float res[4];
    #pragma unroll
    for (int k = 0; k < 4; k++) {
        float m = -INFINITY;
        #pragma unroll
        for (int py = 0; py < 3; py++) {
            int y = 2 * ho - 1 + py;
            if (y < 0 || y >= 128) continue;
            #pragma unroll
            for (int px = 0; px < 3; px++) {
                int x = 2 * wo - 1 + px;
                if (x < 0 || x >= 128) continue;
                m = fmaxf(m, fast_mish(acc[k][py][px]));
            }
        }
        res[k] = m;
    }

    // scatter into feature_map region of d_out
    int lin = lin_pt[(n << 12) + (ho << 6) + wo];
    if (lin >= 0) {
        int b   = lin >> 15;
        int rem = lin & 32767;
        float* base = out + (size_t)b * 2097152 + rem;
        int cob = cg * 16 + wave * 4;
        #pragma unroll
        for (int k = 0; k < 4; k++)
            atomicAdd(base + (size_t)(cob + k) * 32768, res[k]);
    }
}

// ---------------- launcher ----------------
extern "C" void kernel_launch(void* const* d_in, const int* in_sizes, int n_in,
                              void* d_out, int out_size, void* d_ws, size_t ws_size,
                              hipStream_t stream)
{
    const float* rgb   = (const float*)d_in[0];
    const float* sxyz  = (const float*)d_in[1];
    const float* w1    = (const float*)d_in[2];
    const float* w2    = (const float*)d_in[3];
    const int*   index = (const int*)d_in[4];
    float* out = (float*)d_out;

    __hip_bfloat16* feat1 = (__hip_bfloat16*)d_ws;
    int* lin_pt = (int*)((char*)d_ws + FEAT1_BYTES);

    // zero outputs (atomic accumulation targets) and feat1 padding
    hipMemsetAsync(d_out, 0, (size_t)out_size * 4, stream);
    hipMemsetAsync(d_ws, 0, FEAT1_BYTES, stream);

    point_kernel<<<1024, 256, 0, stream>>>(rgb, sxyz, index, out, lin_pt);
    conv1_kernel<<<262144, 256, 0, stream>>>(rgb, w1, feat1);
    conv2_kernel<<<16384, 256, 0, stream>>>(feat1, w2, lin_pt, out);
}

// Round 5
// 4491.106 us; speedup vs baseline: 1.5363x; 1.5363x over previous
//
#include <hip/hip_runtime.h>
#include <hip/hip_bf16.h>
#include <math.h>

// ---------------- problem constants ----------------
#define N_IMG 64
#define H_IN  256
#define W_IN  256
#define CH    64      // PCN_H
#define HP1   128     // spatial after pool1
#define WP1   128
#define HP2   64      // spatial after pool2
#define WP2   64
#define F1_PW 136     // feat1 padded width: col x in [-4,131] stored at x+4

// d_out layout (floats):
//   feature_map (8,64,8,64,64)  : [0, 16777216)
//   counts      (8,1,8,64,64)   : [16777216, 17039360)
//   rgb_map     (8,3,8,64,64)   : [17039360, 17825792)
#define OUT_CNT_BASE 16777216
#define OUT_RGB_BASE 17039360

#define FEAT1_BYTES ((size_t)N_IMG * CH * HP1 * F1_PW * 2)

// mish(x) = x * tanh(softplus(x)) = x * (t^2+2t)/(t^2+2t+2), t=e^x
__device__ __forceinline__ float fast_mish(float x) {
    float xc = fminf(x, 20.0f);
    float t  = __expf(xc);
    float n  = t * (t + 2.0f);
    float y  = x * n / (n + 2.0f);
    return (x > 20.0f) ? x : y;
}

// ------------- kernel 1: per-point binning + rgb/count scatter -------------
__global__ __launch_bounds__(256) void point_kernel(
    const float* __restrict__ rgb,
    const float* __restrict__ sxyz,
    const int*   __restrict__ index,
    float*       __restrict__ out,
    int*         __restrict__ lin_pt)
{
    int p = blockIdx.x * 256 + threadIdx.x;      // 64*64*64 = 262144 points
    int n  = p >> 12;
    int r  = p & 4095;
    int hs = r >> 6;
    int ws = r & 63;

    int row = hs * 4 + 2, col = ws * 4 + 2;
    const float* sx = sxyz + (size_t)n * 3 * 65536;
    float X = sx[row * 256 + col];
    float Y = sx[65536 + row * 256 + col];
    float Z = sx[2 * 65536 + row * 256 + col];

    // replicate JAX op order + trunc-toward-zero int cast
    int hb = (int)(((X + 5.0f) * 64.0f) / 10.0f);
    int wb = (int)(((Y + 5.0f) * 64.0f) / 10.0f);
    int vb = (int)((Z * 8.0f) / 3.0f);
    bool valid = (hb >= 0) & (hb < 64) & (wb >= 0) & (wb < 64) & (vb >= 0) & (vb < 8);

    int b   = index[n];
    int lin = ((b * 8 + vb) * 64 + hb) * 64 + wb;   // b*32768 + vb*4096 + hb*64 + wb
    lin_pt[p] = valid ? lin : -1;

    if (valid) {
        atomicAdd(out + OUT_CNT_BASE + lin, 1.0f);
        int rem = lin & 32767;
        #pragma unroll
        for (int c = 0; c < 3; c++) {
            const float* rg = rgb + (size_t)(n * 3 + c) * 65536;
            float s = 0.0f;
            #pragma unroll
            for (int i = 0; i < 4; i++)
                #pragma unroll
                for (int j = 0; j < 4; j++)
                    s += rg[(hs * 4 + i) * 256 + (ws * 4 + j)];
            atomicAdd(out + OUT_RGB_BASE + b * 98304 + c * 32768 + rem, s * 0.0625f);
        }
    }
}

// ------------- kernel 2: conv1(3->64, dil2) + mish + maxpool3s2 -> feat1 bf16 -------------
// block = (n, r) handles pooled rows {2r, 2r+1} x all 128 wo x all 64 co.
// Input tile staged once in LDS; weights staged in LDS; per-thread register
// accumulation over a 4-co group with 3x3 pool-window recompute (same proven
// structure as conv2_kernel).
__global__ __launch_bounds__(256) void conv1_kernel(
    const float* __restrict__ rgb,
    const float* __restrict__ w1,
    __hip_bfloat16* __restrict__ feat1)
{
    const int r = blockIdx.x & 63;       // pooled row pair
    const int n = blockIdx.x >> 6;
    const int tid = threadIdx.x;
    const int wo = tid & 127;
    const int hsel = tid >> 7;           // 0/1
    const int ho = 2 * r + hsel;

    // LDS: input tile rows 4r-3 .. 4r+5 (9 rows), cols -4..259 (264), 3 ci
    __shared__ float in_t[3 * 9 * 264];   // 28512 B
    __shared__ float wl[64 * 27];         // 6912 B

    const int row0 = 4 * r - 3;
    const float* img = rgb + (size_t)n * 3 * 65536;
    for (int i = tid; i < 3 * 9 * 264; i += 256) {
        int ci = i / (9 * 264);
        int rem = i - ci * (9 * 264);
        int rr = rem / 264;
        int cc = rem - rr * 264;
        int gy = row0 + rr;
        int gx = cc - 4;
        float v = 0.0f;
        if (gy >= 0 && gy < 256 && gx >= 0 && gx < 256)
            v = img[ci * 65536 + gy * 256 + gx];
        in_t[i] = v;
    }
    for (int i = tid; i < 64 * 27; i += 256) wl[i] = w1[i];
    __syncthreads();

    #pragma unroll 1
    for (int cg = 0; cg < 16; cg++) {
        float acc[4][3][3];
        #pragma unroll
        for (int k = 0; k < 4; k++)
            #pragma unroll
            for (int a = 0; a < 3; a++)
                #pragma unroll
                for (int bq = 0; bq < 3; bq++) acc[k][a][bq] = 0.0f;

        #pragma unroll
        for (int ci = 0; ci < 3; ci++) {
            float wr[4][9];
            #pragma unroll
            for (int k = 0; k < 4; k++)
                #pragma unroll
                for (int t = 0; t < 9; t++)
                    wr[k][t] = wl[(cg * 4 + k) * 27 + ci * 9 + t];

            #pragma unroll
            for (int dr = -3; dr <= 3; dr++) {
                const float* rowp = &in_t[(ci * 9 + (2 * hsel + dr + 3)) * 264 + 2 * wo];
                float v[8];
                #pragma unroll
                for (int j = 0; j < 8; j++) v[j] = rowp[j];

                #pragma unroll
                for (int py = 0; py < 3; py++) {
                    int kyo = dr - (py - 1);
                    if (kyo == -2 || kyo == 0 || kyo == 2) {
                        int ky = kyo / 2 + 1;
                        #pragma unroll
                        for (int k = 0; k < 4; k++)
                            #pragma unroll
                            for (int px = 0; px < 3; px++)
                                #pragma unroll
                                for (int kx = 0; kx < 3; kx++)
                                    acc[k][py][px] += wr[k][ky * 3 + kx] * v[(px - 1) + 2 * (kx - 1) + 4];
                    }
                }
            }
        }

        // mish + 3x3 s2 maxpool (pre-pool grid is 256x256 here)
        #pragma unroll
        for (int k = 0; k < 4; k++) {
            float m = -INFINITY;
            #pragma unroll
            for (int py = 0; py < 3; py++) {
                int y = 2 * ho - 1 + py;
                if (y < 0 || y >= 256) continue;
                #pragma unroll
                for (int px = 0; px < 3; px++) {
                    int x = 2 * wo - 1 + px;
                    if (x < 0 || x >= 256) continue;
                    m = fmaxf(m, fast_mish(acc[k][py][px]));
                }
            }
            feat1[((size_t)(n * 64 + cg * 4 + k) * HP1 + ho) * F1_PW + (wo + 4)] =
                __float2bfloat16(m);
        }
    }
}

// ------------- kernel 3: conv2(64->64, dil2) + mish + maxpool3s2 + feature scatter -------------
__global__ __launch_bounds__(256) void conv2_kernel(
    const __hip_bfloat16* __restrict__ feat1,
    const float* __restrict__ w2,
    const int*   __restrict__ lin_pt,
    float*       __restrict__ out)
{
    // grid: ((n*4 + cg)*64 + ho); block: 4 waves x 64 lanes(wo); thread: 4 co
    int bid  = blockIdx.x;
    int ho   = bid & 63;
    int cg   = (bid >> 6) & 3;
    int n    = bid >> 8;
    int wo   = threadIdx.x & 63;
    int wave = threadIdx.x >> 6;

    __shared__ float wl[16 * 64 * 9];   // 16 co x 64 ci x 9 taps = 36 KB
    {
        const float* wsrc = w2 + cg * 16 * 576;   // co block contiguous
        for (int i = threadIdx.x; i < 9216; i += 256) wl[i] = wsrc[i];
    }
    __syncthreads();

    float acc[4][3][3];
    #pragma unroll
    for (int k = 0; k < 4; k++)
        #pragma unroll
        for (int a = 0; a < 3; a++)
            #pragma unroll
            for (int bq = 0; bq < 3; bq++) acc[k][a][bq] = 0.0f;

    const __hip_bfloat16* f1n = feat1 + (size_t)n * CH * HP1 * F1_PW;

    for (int ci = 0; ci < 64; ci++) {
        // hoist this ci's 4x9 weights to registers
        float wr[4][9];
        #pragma unroll
        for (int k = 0; k < 4; k++)
            #pragma unroll
            for (int t = 0; t < 9; t++)
                wr[k][t] = wl[((wave * 4 + k) * 64 + ci) * 9 + t];

        const __hip_bfloat16* fp = f1n + (size_t)ci * HP1 * F1_PW;
        #pragma unroll
        for (int dr = -3; dr <= 3; dr++) {
            int rr = 2 * ho + dr;
            float v[8];
            if (rr >= 0 && rr < 128) {
                const unsigned int* rp32 =
                    reinterpret_cast<const unsigned int*>(fp + rr * F1_PW + 2 * wo); // x=2wo-4 stored at col 2wo
                #pragma unroll
                for (int k = 0; k < 4; k++) {
                    unsigned int u = rp32[k];
                    v[2 * k]     = __uint_as_float(u << 16);
                    v[2 * k + 1] = __uint_as_float(u & 0xFFFF0000u);
                }
            } else {
                #pragma unroll
                for (int j = 0; j < 8; j++) v[j] = 0.0f;
            }
            #pragma unroll
            for (int py = 0; py < 3; py++) {
                int kyo = dr - (py - 1);
                if (kyo == -2 || kyo == 0 || kyo == 2) {
                    int ky = kyo / 2 + 1;
                    #pragma unroll
                    for (int k = 0; k < 4; k++)
                        #pragma unroll
                        for (int px = 0; px < 3; px++)
                            #pragma unroll
                            for (int kx = 0; kx < 3; kx++)
                                acc[k][py][px] += wr[k][ky * 3 + kx] * v[(px - 1) + 2 * (kx - 1) + 4];
                }
            }
        }
    }

    // mish + 3x3 s2 maxpool (pooled coord = (ho,wo))
    float res[4];
    #pragma unroll
    for (int k = 0; k < 4; k++) {
        float m = -INFINITY;
        #pragma unroll
        for (int py = 0; py < 3; py++) {
            int y = 2 * ho - 1 + py;
            if (y < 0 || y >= 128) continue;
            #pragma unroll
            for (int px = 0; px < 3; px++) {
                int x = 2 * wo - 1 + px;
                if (x < 0 || x >= 128) continue;
                m = fmaxf(m, fast_mish(acc[k][py][px]));
            }
        }
        res[k] = m;
    }

    // scatter into feature_map region of d_out
    int lin = lin_pt[(n << 12) + (ho << 6) + wo];
    if (lin >= 0) {
        int b   = lin >> 15;
        int rem = lin & 32767;
        float* base = out + (size_t)b * 2097152 + rem;
        int cob = cg * 16 + wave * 4;
        #pragma unroll
        for (int k = 0; k < 4; k++)
            atomicAdd(base + (size_t)(cob + k) * 32768, res[k]);
    }
}

// ---------------- launcher ----------------
extern "C" void kernel_launch(void* const* d_in, const int* in_sizes, int n_in,
                              void* d_out, int out_size, void* d_ws, size_t ws_size,
                              hipStream_t stream)
{
    const float* rgb   = (const float*)d_in[0];
    const float* sxyz  = (const float*)d_in[1];
    const float* w1    = (const float*)d_in[2];
    const float* w2    = (const float*)d_in[3];
    const int*   index = (const int*)d_in[4];
    float* out = (float*)d_out;

    __hip_bfloat16* feat1 = (__hip_bfloat16*)d_ws;
    int* lin_pt = (int*)((char*)d_ws + FEAT1_BYTES);

    // zero outputs (atomic accumulation targets) and feat1 padding
    hipMemsetAsync(d_out, 0, (size_t)out_size * 4, stream);
    hipMemsetAsync(d_ws, 0, FEAT1_BYTES, stream);

    point_kernel<<<1024, 256, 0, stream>>>(rgb, sxyz, index, out, lin_pt);
    conv1_kernel<<<4096, 256, 0, stream>>>(rgb, w1, feat1);
    conv2_kernel<<<16384, 256, 0, stream>>>(feat1, w2, lin_pt, out);
}

// Round 6
// 2029.207 us; speedup vs baseline: 3.4002x; 2.2132x over previous
//
#include <hip/hip_runtime.h>
#include <hip/hip_bf16.h>
#include <math.h>

// ---------------- problem constants ----------------
#define N_IMG 64
#define CH    64      // PCN_H
#define HP1   128     // spatial after pool1
#define F1_R  136     // feat1 padded rows: row y stored at y+4  (used 1..133)
#define F1_C  136     // feat1 padded cols: col x stored at x+4  (used 2..133)
// feat1 channel-last: [n][F1_R][F1_C][64] bf16
#define F1_IMG_STRIDE ((size_t)F1_R * F1_C * 64)
#define F1_ROW_STRIDE (F1_C * 64)
#define FEAT1_BYTES ((size_t)N_IMG * F1_IMG_STRIDE * 2)

// d_out layout (floats):
//   feature_map (8,64,8,64,64)  : [0, 16777216)
//   counts      (8,1,8,64,64)   : [16777216, 17039360)
//   rgb_map     (8,3,8,64,64)   : [17039360, 17825792)
#define OUT_CNT_BASE 16777216
#define OUT_RGB_BASE 17039360

typedef short bf16x8 __attribute__((ext_vector_type(8)));
typedef float f32x4  __attribute__((ext_vector_type(4)));

// mish(x) = x * tanh(softplus(x)) = x * (t^2+2t)/(t^2+2t+2), t=e^x
__device__ __forceinline__ float fast_mish(float x) {
    float xc = fminf(x, 20.0f);
    float t  = __expf(xc);
    float n  = t * (t + 2.0f);
    float y  = x * n / (n + 2.0f);
    return (x > 20.0f) ? x : y;
}

// float -> bf16 bits, round-to-nearest-even (handles +-inf correctly)
__device__ __forceinline__ unsigned short f2bf(float f) {
    unsigned u = __float_as_uint(f);
    unsigned r = (u + 0x7FFFu + ((u >> 16) & 1u)) >> 16;
    return (unsigned short)r;
}

// ------------- kernel 1: per-point binning + rgb/count scatter -------------
__global__ __launch_bounds__(256) void point_kernel(
    const float* __restrict__ rgb,
    const float* __restrict__ sxyz,
    const int*   __restrict__ index,
    float*       __restrict__ out,
    int*         __restrict__ lin_pt)
{
    int p = blockIdx.x * 256 + threadIdx.x;      // 64*64*64 = 262144 points
    int n  = p >> 12;
    int r  = p & 4095;
    int hs = r >> 6;
    int ws = r & 63;

    int row = hs * 4 + 2, col = ws * 4 + 2;
    const float* sx = sxyz + (size_t)n * 3 * 65536;
    float X = sx[row * 256 + col];
    float Y = sx[65536 + row * 256 + col];
    float Z = sx[2 * 65536 + row * 256 + col];

    // replicate JAX op order + trunc-toward-zero int cast
    int hb = (int)(((X + 5.0f) * 64.0f) / 10.0f);
    int wb = (int)(((Y + 5.0f) * 64.0f) / 10.0f);
    int vb = (int)((Z * 8.0f) / 3.0f);
    bool valid = (hb >= 0) & (hb < 64) & (wb >= 0) & (wb < 64) & (vb >= 0) & (vb < 8);

    int b   = index[n];
    int lin = ((b * 8 + vb) * 64 + hb) * 64 + wb;
    lin_pt[p] = valid ? lin : -1;

    if (valid) {
        atomicAdd(out + OUT_CNT_BASE + lin, 1.0f);
        int rem = lin & 32767;
        #pragma unroll
        for (int c = 0; c < 3; c++) {
            const float* rg = rgb + (size_t)(n * 3 + c) * 65536;
            float s = 0.0f;
            #pragma unroll
            for (int i = 0; i < 4; i++)
                #pragma unroll
                for (int j = 0; j < 4; j++)
                    s += rg[(hs * 4 + i) * 256 + (ws * 4 + j)];
            atomicAdd(out + OUT_RGB_BASE + b * 98304 + c * 32768 + rem, s * 0.0625f);
        }
    }
}

// ------------- kernel 2: conv1(3->64, dil2) + mish + maxpool3s2 -> feat1 (channel-last bf16) ---
__global__ __launch_bounds__(256) void conv1_kernel(
    const float* __restrict__ rgb,
    const float* __restrict__ w1,
    __hip_bfloat16* __restrict__ feat1)
{
    const int r = blockIdx.x & 63;       // pooled row pair
    const int n = blockIdx.x >> 6;
    const int tid = threadIdx.x;
    const int wo = tid & 127;
    const int hsel = tid >> 7;           // 0/1
    const int ho = 2 * r + hsel;

    __shared__ float in_t[3 * 9 * 264];   // rows 4r-3..4r+5, cols -4..259
    __shared__ float wl[64 * 27];

    const int row0 = 4 * r - 3;
    const float* img = rgb + (size_t)n * 3 * 65536;
    for (int i = tid; i < 3 * 9 * 264; i += 256) {
        int ci = i / (9 * 264);
        int rem = i - ci * (9 * 264);
        int rr = rem / 264;
        int cc = rem - rr * 264;
        int gy = row0 + rr;
        int gx = cc - 4;
        float v = 0.0f;
        if (gy >= 0 && gy < 256 && gx >= 0 && gx < 256)
            v = img[ci * 65536 + gy * 256 + gx];
        in_t[i] = v;
    }
    for (int i = tid; i < 64 * 27; i += 256) wl[i] = w1[i];
    __syncthreads();

    __hip_bfloat16* fbase = feat1 + (size_t)n * F1_IMG_STRIDE
                          + (size_t)(ho + 4) * F1_ROW_STRIDE + (size_t)(wo + 4) * 64;

    #pragma unroll 1
    for (int cg = 0; cg < 16; cg++) {
        float acc[4][3][3];
        #pragma unroll
        for (int k = 0; k < 4; k++)
            #pragma unroll
            for (int a = 0; a < 3; a++)
                #pragma unroll
                for (int bq = 0; bq < 3; bq++) acc[k][a][bq] = 0.0f;

        #pragma unroll
        for (int ci = 0; ci < 3; ci++) {
            float wr[4][9];
            #pragma unroll
            for (int k = 0; k < 4; k++)
                #pragma unroll
                for (int t = 0; t < 9; t++)
                    wr[k][t] = wl[(cg * 4 + k) * 27 + ci * 9 + t];

            #pragma unroll
            for (int dr = -3; dr <= 3; dr++) {
                const float* rowp = &in_t[(ci * 9 + (2 * hsel + dr + 3)) * 264 + 2 * wo];
                float v[8];
                #pragma unroll
                for (int j = 0; j < 8; j++) v[j] = rowp[j];

                #pragma unroll
                for (int py = 0; py < 3; py++) {
                    int kyo = dr - (py - 1);
                    if (kyo == -2 || kyo == 0 || kyo == 2) {
                        int ky = kyo / 2 + 1;
                        #pragma unroll
                        for (int k = 0; k < 4; k++)
                            #pragma unroll
                            for (int px = 0; px < 3; px++)
                                #pragma unroll
                                for (int kx = 0; kx < 3; kx++)
                                    acc[k][py][px] += wr[k][ky * 3 + kx] * v[(px - 1) + 2 * (kx - 1) + 4];
                    }
                }
            }
        }

        // mish + 3x3 s2 maxpool, pack 4 co -> one 8B store (channel-last)
        unsigned long long pk = 0;
        #pragma unroll
        for (int k = 0; k < 4; k++) {
            float m = -INFINITY;
            #pragma unroll
            for (int py = 0; py < 3; py++) {
                int y = 2 * ho - 1 + py;
                if (y < 0 || y >= 256) continue;
                #pragma unroll
                for (int px = 0; px < 3; px++) {
                    int x = 2 * wo - 1 + px;
                    if (x < 0 || x >= 256) continue;
                    m = fmaxf(m, fast_mish(acc[k][py][px]));
                }
            }
            pk |= (unsigned long long)f2bf(m) << (16 * k);
        }
        *reinterpret_cast<unsigned long long*>(fbase + cg * 4) = pk;
    }
}

// ------------- kernel 3: conv2 via MFMA + mish + maxpool3s2 + feature scatter -------------
// block = (n, pr): computes pre-pool rows 4pr-1 .. 4pr+3 (5 rows x 128 cols x 64 co),
// pools rows 2pr, 2pr+1 in LDS, scatters. 10 waves: wave w -> row (w>>1), col-half (w&1).
__global__ __launch_bounds__(640, 3) void conv2_mfma_kernel(
    const __hip_bfloat16* __restrict__ feat1,
    const float* __restrict__ w2,
    const int*   __restrict__ lin_pt,
    float*       __restrict__ out)
{
    // XCD-chunked swizzle: 2048 blocks -> each XCD gets 8 whole images (L2 reuse)
    int b2 = ((blockIdx.x & 7) << 8) + (blockIdx.x >> 3);
    const int n  = b2 >> 5;
    const int pr = b2 & 31;
    const int tid  = threadIdx.x;
    const int lane = tid & 63;
    const int w    = tid >> 6;        // 0..9
    const int lrow = w >> 1;          // local pre-pool row 0..4
    const int chalf = w & 1;          // col half
    const int y = 4 * pr - 1 + lrow;  // global pre-pool row (-1..127)

    __shared__ __align__(16) char smem[81920];   // weights (73728B) then pool tile (81920B)

    // ---- stage W2 -> LDS bf16, layout [tap][co][ci], XOR-swizzled (T2) ----
    for (int i = tid; i < 36864; i += 640) {
        int t  = i >> 12;           // 0..8
        int co = (i >> 6) & 63;
        int ci = i & 63;
        unsigned short h = f2bf(w2[(co * 64 + ci) * 9 + t]);
        int byte = ((((t << 6) + co) << 6) + ci) << 1;
        byte ^= (co & 7) << 4;
        *reinterpret_cast<unsigned short*>(smem + byte) = h;
    }
    __syncthreads();

    f32x4 acc[4][4];
    #pragma unroll
    for (int mt = 0; mt < 4; mt++)
        #pragma unroll
        for (int nt = 0; nt < 4; nt++)
            acc[mt][nt] = (f32x4){0.f, 0.f, 0.f, 0.f};

    // B lane base: row (y-2)+4 = y+2, col (lane&15) + chalf*64 + (-2) + 4
    const __hip_bfloat16* bbase = feat1 + (size_t)n * F1_IMG_STRIDE
        + ((size_t)(y + 2) * F1_C + (lane & 15) + chalf * 64 + 2) * 64
        + ((lane >> 4) << 3);

    #pragma unroll
    for (int ky = 0; ky < 3; ky++) {
        #pragma unroll
        for (int kx = 0; kx < 3; kx++) {
            const int t = ky * 3 + kx;
            #pragma unroll
            for (int s = 0; s < 2; s++) {
                bf16x8 a[4];
                #pragma unroll
                for (int mt = 0; mt < 4; mt++) {
                    int co = mt * 16 + (lane & 15);
                    int byte = ((((t << 6) + co) << 6) + (s << 5) + ((lane >> 4) << 3)) << 1;
                    byte ^= (co & 7) << 4;
                    a[mt] = *reinterpret_cast<const bf16x8*>(smem + byte);
                }
                const __hip_bfloat16* bp = bbase + (ky * 2 * F1_C + kx * 2) * 64 + s * 32;
                #pragma unroll
                for (int nt = 0; nt < 4; nt++) {
                    bf16x8 b = *reinterpret_cast<const bf16x8*>(bp + nt * 1024);
                    #pragma unroll
                    for (int mt = 0; mt < 4; mt++)
                        acc[mt][nt] = __builtin_amdgcn_mfma_f32_16x16x32_bf16(
                            a[mt], b, acc[mt][nt], 0, 0, 0);
                }
            }
        }
    }

    __syncthreads();   // weights region now dead; reuse LDS for pool tile

    // ---- epilogue: mish -> bf16 -> pool tile LDS [5][128][64], XOR ((col&7)<<4) ----
    const bool deadrow = (y < 0);   // maxpool padding row = -inf
    #pragma unroll
    for (int nt = 0; nt < 4; nt++) {
        int col = chalf * 64 + nt * 16 + (lane & 15);
        #pragma unroll
        for (int mt = 0; mt < 4; mt++) {
            int co0 = mt * 16 + ((lane >> 4) << 2);
            unsigned long long pk = 0;
            #pragma unroll
            for (int r4 = 0; r4 < 4; r4++) {
                float v = deadrow ? -INFINITY : fast_mish(acc[mt][nt][r4]);
                pk |= (unsigned long long)f2bf(v) << (16 * r4);
            }
            int byte = ((((lrow * 128 + col) << 6) + co0) << 1);
            byte ^= (col & 7) << 4;
            *reinterpret_cast<unsigned long long*>(smem + byte) = pk;
        }
    }
    __syncthreads();

    // ---- pool 3x3 s2 over LDS tile + scatter ----
    const int pbase = (n << 12) + ((pr << 1) << 6);
    for (int i = tid; i < 8192; i += 640) {
        int pp = i >> 12;          // 0/1 -> pooled row 2pr+pp
        int c  = (i >> 6) & 63;    // pooled col
        int co = i & 63;
        float m = -INFINITY;
        #pragma unroll
        for (int dy = 0; dy < 3; dy++) {
            int lr = 2 * pp + dy;
            #pragma unroll
            for (int dx = 0; dx < 3; dx++) {
                int x = 2 * c - 1 + dx;
                if (x < 0 || x > 127) continue;
                int byte = ((((lr * 128 + x) << 6) + co) << 1) ^ ((x & 7) << 4);
                unsigned short hv = *reinterpret_cast<const unsigned short*>(smem + byte);
                m = fmaxf(m, __uint_as_float((unsigned)hv << 16));
            }
        }
        int lin = lin_pt[pbase + (pp << 6) + c];
        if (lin >= 0)
            atomicAdd(out + (size_t)(lin >> 15) * 2097152 + (size_t)co * 32768 + (lin & 32767), m);
    }
}

// ---------------- launcher ----------------
extern "C" void kernel_launch(void* const* d_in, const int* in_sizes, int n_in,
                              void* d_out, int out_size, void* d_ws, size_t ws_size,
                              hipStream_t stream)
{
    const float* rgb   = (const float*)d_in[0];
    const float* sxyz  = (const float*)d_in[1];
    const float* w1    = (const float*)d_in[2];
    const float* w2    = (const float*)d_in[3];
    const int*   index = (const int*)d_in[4];
    float* out = (float*)d_out;

    __hip_bfloat16* feat1 = (__hip_bfloat16*)d_ws;
    int* lin_pt = (int*)((char*)d_ws + FEAT1_BYTES);

    hipMemsetAsync(d_out, 0, (size_t)out_size * 4, stream);
    hipMemsetAsync(d_ws, 0, FEAT1_BYTES, stream);   // zeroes feat1 padding too

    point_kernel<<<1024, 256, 0, stream>>>(rgb, sxyz, index, out, lin_pt);
    conv1_kernel<<<4096, 256, 0, stream>>>(rgb, w1, feat1);
    conv2_mfma_kernel<<<2048, 640, 0, stream>>>(feat1, w2, lin_pt, out);
}

// Round 7
// 1649.036 us; speedup vs baseline: 4.1841x; 1.2305x over previous
//
#include <hip/hip_runtime.h>
#include <hip/hip_bf16.h>
#include <math.h>

// ---------------- problem constants ----------------
#define N_IMG 64
#define CH    64      // PCN_H
#define F1_R  136     // feat1 padded rows: row y stored at y+4  (used 1..133)
#define F1_C  136     // feat1 padded cols: col x stored at x+4  (used 2..133)
// feat1 channel-last: [n][F1_R][F1_C][64] bf16
#define F1_IMG_STRIDE ((size_t)F1_R * F1_C * 64)
#define F1_ROW_STRIDE (F1_C * 64)
#define FEAT1_BYTES ((size_t)N_IMG * F1_IMG_STRIDE * 2)

// d_out layout (floats):
//   feature_map (8,64,8,64,64)  : [0, 16777216)
//   counts      (8,1,8,64,64)   : [16777216, 17039360)
//   rgb_map     (8,3,8,64,64)   : [17039360, 17825792)
#define OUT_CNT_BASE 16777216
#define OUT_RGB_BASE 17039360

typedef short bf16x8 __attribute__((ext_vector_type(8)));
typedef float f32x4  __attribute__((ext_vector_type(4)));

// mish(x) = x * tanh(softplus(x)) = x * (t^2+2t)/(t^2+2t+2), t=e^x
__device__ __forceinline__ float fast_mish(float x) {
    float xc = fminf(x, 20.0f);
    float t  = __expf(xc);
    float n  = t * (t + 2.0f);
    float y  = x * n / (n + 2.0f);
    return (x > 20.0f) ? x : y;
}

// float -> bf16 bits, round-to-nearest-even (handles +-inf correctly)
__device__ __forceinline__ unsigned short f2bf(float f) {
    unsigned u = __float_as_uint(f);
    unsigned r = (u + 0x7FFFu + ((u >> 16) & 1u)) >> 16;
    return (unsigned short)r;
}

// ------------- kernel 1: per-point binning + rgb/count scatter -------------
__global__ __launch_bounds__(256) void point_kernel(
    const float* __restrict__ rgb,
    const float* __restrict__ sxyz,
    const int*   __restrict__ index,
    float*       __restrict__ out,
    int*         __restrict__ lin_pt)
{
    int p = blockIdx.x * 256 + threadIdx.x;      // 64*64*64 = 262144 points
    int n  = p >> 12;
    int r  = p & 4095;
    int hs = r >> 6;
    int ws = r & 63;

    int row = hs * 4 + 2, col = ws * 4 + 2;
    const float* sx = sxyz + (size_t)n * 3 * 65536;
    float X = sx[row * 256 + col];
    float Y = sx[65536 + row * 256 + col];
    float Z = sx[2 * 65536 + row * 256 + col];

    // replicate JAX op order + trunc-toward-zero int cast
    int hb = (int)(((X + 5.0f) * 64.0f) / 10.0f);
    int wb = (int)(((Y + 5.0f) * 64.0f) / 10.0f);
    int vb = (int)((Z * 8.0f) / 3.0f);
    bool valid = (hb >= 0) & (hb < 64) & (wb >= 0) & (wb < 64) & (vb >= 0) & (vb < 8);

    int b   = index[n];
    int lin = ((b * 8 + vb) * 64 + hb) * 64 + wb;
    lin_pt[p] = valid ? lin : -1;

    if (valid) {
        atomicAdd(out + OUT_CNT_BASE + lin, 1.0f);
        int rem = lin & 32767;
        #pragma unroll
        for (int c = 0; c < 3; c++) {
            const float* rg = rgb + (size_t)(n * 3 + c) * 65536;
            float s = 0.0f;
            #pragma unroll
            for (int i = 0; i < 4; i++)
                #pragma unroll
                for (int j = 0; j < 4; j++)
                    s += rg[(hs * 4 + i) * 256 + (ws * 4 + j)];
            atomicAdd(out + OUT_RGB_BASE + b * 98304 + c * 32768 + rem, s * 0.0625f);
        }
    }
}

// ------------- kernel 2: conv1 via MFMA + mish + maxpool3s2 -> feat1 (channel-last) ----------
// GEMM view: M=64 co, K=32 (3ci x 9taps pad), N=spatial.
// block = (n, pr): pre-pool rows 4pr-1..4pr+3 (5 rows x 256 cols), pools rows 2pr,2pr+1.
// 16 waves x 5 (row,col-tile) tasks x 4 m-tiles; single K-step MFMA.
__global__ __launch_bounds__(1024) void conv1_mfma_kernel(
    const float* __restrict__ rgb,
    const float* __restrict__ w1,
    __hip_bfloat16* __restrict__ feat1)
{
    int b2 = ((blockIdx.x & 7) << 9) + (blockIdx.x >> 3);   // XCD-chunked swizzle (4096 = 8x512)
    const int n  = b2 >> 6;
    const int pr = b2 & 63;
    const int tid  = threadIdx.x;
    const int lane = tid & 63;
    const int w    = tid >> 6;       // 0..15

    __shared__ __align__(16) char smem[81920];
    // MFMA phase: wlds [64co][32k] bf16 @0 (4KB); in_t [3ci][9r][264c]+16 zeros @4096 (14.3KB)
    // epilogue : pool tile [5][256][32co] bf16 @0 (80KB)
    unsigned short* wlds = (unsigned short*)smem;
    unsigned short* in_t = (unsigned short*)(smem + 4096);

    // ---- stage weights [co][k], k = ci*9 + ky*3 + kx (k>=27 -> 0)
    for (int i = tid; i < 2048; i += 1024) {
        int co = i >> 5, k = i & 31;
        wlds[i] = (k < 27) ? f2bf(w1[co * 27 + k]) : (unsigned short)0;
    }
    // ---- stage input tile: rows 4pr-3..4pr+5, cols -2..261, bf16; tail 16 zeros
    {
        const float* img = rgb + (size_t)n * 3 * 65536;
        for (int i = tid; i < 7144; i += 1024) {
            unsigned short v = 0;
            if (i < 7128) {
                int ci  = i / 2376;
                int rem = i - ci * 2376;
                int rr  = rem / 264;
                int cc  = rem - rr * 264;
                int gy  = 4 * pr - 3 + rr;
                int gx  = cc - 2;
                if (gy >= 0 && gy < 256 && gx >= 0 && gx < 256)
                    v = f2bf(img[ci * 65536 + gy * 256 + gx]);
            }
            in_t[i] = v;
        }
    }
    __syncthreads();

    // ---- per-lane B gather offsets (bytes) for k = (lane>>4)*8 + j
    int boff[8];
    #pragma unroll
    for (int j = 0; j < 8; j++) {
        int k = ((lane >> 4) << 3) + j;
        if (k < 27) {
            int ci = k / 9, t = k - 9 * ci, ky = t / 3, kx = t - 3 * ky;
            boff[j] = (ci * 2376 + 2 * ky * 264 + 2 * kx + (lane & 15)) * 2;
        } else {
            boff[j] = 7128 * 2;     // zero slot
        }
    }

    // ---- A fragments (weights), k-map identical to B: k = (lane>>4)*8 + j
    bf16x8 a[4];
    #pragma unroll
    for (int mt = 0; mt < 4; mt++)
        a[mt] = *reinterpret_cast<const bf16x8*>(
            wlds + (mt * 16 + (lane & 15)) * 32 + ((lane >> 4) << 3));

    f32x4 acc[5][4];
    #pragma unroll
    for (int tt = 0; tt < 5; tt++)
        #pragma unroll
        for (int mt = 0; mt < 4; mt++)
            acc[tt][mt] = (f32x4){0.f, 0.f, 0.f, 0.f};

    const char* in_b = (const char*)in_t;
    #pragma unroll
    for (int tt = 0; tt < 5; tt++) {
        int t5 = w * 5 + tt;             // 0..79: 5 rows x 16 col-tiles
        int r  = t5 >> 4;
        int x0 = (t5 & 15) << 4;
        int base = (r * 264 + x0) * 2;
        unsigned short e[8];
        #pragma unroll
        for (int j = 0; j < 8; j++)
            e[j] = *reinterpret_cast<const unsigned short*>(in_b + base + boff[j]);
        bf16x8 b;
        #pragma unroll
        for (int j = 0; j < 8; j++) b[j] = (short)e[j];
        #pragma unroll
        for (int mt = 0; mt < 4; mt++)
            acc[tt][mt] = __builtin_amdgcn_mfma_f32_16x16x32_bf16(a[mt], b, acc[tt][mt], 0, 0, 0);
    }

    __syncthreads();   // wlds/in_t dead; reuse LDS as pool tile

    unsigned short* pool = (unsigned short*)smem;
    const int ybase = 4 * pr - 1;

    #pragma unroll 1
    for (int p = 0; p < 2; p++) {       // co half
        // write mish'd pre-pool values for co in [p*32, p*32+32)
        #pragma unroll
        for (int tt = 0; tt < 5; tt++) {
            int t5 = w * 5 + tt;
            int r  = t5 >> 4;
            int x  = ((t5 & 15) << 4) + (lane & 15);
            bool dead = (ybase + r) < 0;      // y=-1 pad row -> -inf
            #pragma unroll
            for (int m2 = 0; m2 < 2; m2++) {
                int mt  = p * 2 + m2;
                int col = m2 * 16 + ((lane >> 4) << 2);   // co & 31 (4-aligned)
                unsigned long long pk = 0;
                #pragma unroll
                for (int q = 0; q < 4; q++) {
                    float v = dead ? -INFINITY : fast_mish(acc[tt][mt][q]);
                    pk |= (unsigned long long)f2bf(v) << (16 * q);
                }
                int byte = (((r * 256 + x) * 32) + col) * 2;
                byte ^= (x & 7) << 4;
                *reinterpret_cast<unsigned long long*>((char*)pool + byte) = pk;
            }
        }
        __syncthreads();
        // 3x3 s2 pool + channel-last feat1 store for this co half
        for (int i = tid; i < 8192; i += 1024) {
            int pp = i >> 12;            // pooled row 2pr+pp
            int c  = (i >> 5) & 127;     // pooled col
            int cl = i & 31;
            float m = -INFINITY;
            #pragma unroll
            for (int dy = 0; dy < 3; dy++) {
                int lr = 2 * pp + dy;
                #pragma unroll
                for (int dx = 0; dx < 3; dx++) {
                    int x = 2 * c - 1 + dx;
                    if (x < 0) continue;                  // x<=255 always
                    int byte = ((((lr * 256) + x) * 32) + cl) * 2;
                    byte ^= (x & 7) << 4;
                    unsigned short hv = *reinterpret_cast<const unsigned short*>((char*)pool + byte);
                    m = fmaxf(m, __uint_as_float((unsigned)hv << 16));
                }
            }
            unsigned short* dst = (unsigned short*)(feat1 + (size_t)n * F1_IMG_STRIDE
                + (size_t)(2 * pr + pp + 4) * F1_ROW_STRIDE + (size_t)(c + 4) * 64 + p * 32 + cl);
            *dst = f2bf(m);
        }
        __syncthreads();
    }
}

// ------------- kernel 3: conv2 via MFMA + mish + maxpool3s2 + feature scatter -------------
// block = (n, pr): computes pre-pool rows 4pr-1 .. 4pr+3 (5 rows x 128 cols x 64 co),
// pools rows 2pr, 2pr+1 in LDS, scatters. 10 waves: wave w -> row (w>>1), col-half (w&1).
__global__ __launch_bounds__(640, 3) void conv2_mfma_kernel(
    const __hip_bfloat16* __restrict__ feat1,
    const float* __restrict__ w2,
    const int*   __restrict__ lin_pt,
    float*       __restrict__ out)
{
    // XCD-chunked swizzle: 2048 blocks -> each XCD gets 8 whole images (L2 reuse)
    int b2 = ((blockIdx.x & 7) << 8) + (blockIdx.x >> 3);
    const int n  = b2 >> 5;
    const int pr = b2 & 31;
    const int tid  = threadIdx.x;
    const int lane = tid & 63;
    const int w    = tid >> 6;        // 0..9
    const int lrow = w >> 1;          // local pre-pool row 0..4
    const int chalf = w & 1;          // col half
    const int y = 4 * pr - 1 + lrow;  // global pre-pool row (-1..127)

    __shared__ __align__(16) char smem[81920];   // weights (73728B) then pool tile (81920B)

    // ---- stage W2 -> LDS bf16, layout [tap][co][ci], XOR-swizzled (T2) ----
    for (int i = tid; i < 36864; i += 640) {
        int t  = i >> 12;           // 0..8
        int co = (i >> 6) & 63;
        int ci = i & 63;
        unsigned short h = f2bf(w2[(co * 64 + ci) * 9 + t]);
        int byte = ((((t << 6) + co) << 6) + ci) << 1;
        byte ^= (co & 7) << 4;
        *reinterpret_cast<unsigned short*>(smem + byte) = h;
    }
    __syncthreads();

    f32x4 acc[4][4];
    #pragma unroll
    for (int mt = 0; mt < 4; mt++)
        #pragma unroll
        for (int nt = 0; nt < 4; nt++)
            acc[mt][nt] = (f32x4){0.f, 0.f, 0.f, 0.f};

    // B lane base: row (y-2)+4 = y+2, col (lane&15) + chalf*64 + (-2) + 4
    const __hip_bfloat16* bbase = feat1 + (size_t)n * F1_IMG_STRIDE
        + ((size_t)(y + 2) * F1_C + (lane & 15) + chalf * 64 + 2) * 64
        + ((lane >> 4) << 3);

    #pragma unroll
    for (int ky = 0; ky < 3; ky++) {
        #pragma unroll
        for (int kx = 0; kx < 3; kx++) {
            const int t = ky * 3 + kx;
            #pragma unroll
            for (int s = 0; s < 2; s++) {
                bf16x8 a[4];
                #pragma unroll
                for (int mt = 0; mt < 4; mt++) {
                    int co = mt * 16 + (lane & 15);
                    int byte = ((((t << 6) + co) << 6) + (s << 5) + ((lane >> 4) << 3)) << 1;
                    byte ^= (co & 7) << 4;
                    a[mt] = *reinterpret_cast<const bf16x8*>(smem + byte);
                }
                const __hip_bfloat16* bp = bbase + (ky * 2 * F1_C + kx * 2) * 64 + s * 32;
                #pragma unroll
                for (int nt = 0; nt < 4; nt++) {
                    bf16x8 b = *reinterpret_cast<const bf16x8*>(bp + nt * 1024);
                    #pragma unroll
                    for (int mt = 0; mt < 4; mt++)
                        acc[mt][nt] = __builtin_amdgcn_mfma_f32_16x16x32_bf16(
                            a[mt], b, acc[mt][nt], 0, 0, 0);
                }
            }
        }
    }

    __syncthreads();   // weights region now dead; reuse LDS for pool tile

    // ---- epilogue: mish -> bf16 -> pool tile LDS [5][128][64], XOR ((col&7)<<4) ----
    const bool deadrow = (y < 0);   // maxpool padding row = -inf
    #pragma unroll
    for (int nt = 0; nt < 4; nt++) {
        int col = chalf * 64 + nt * 16 + (lane & 15);
        #pragma unroll
        for (int mt = 0; mt < 4; mt++) {
            int co0 = mt * 16 + ((lane >> 4) << 2);
            unsigned long long pk = 0;
            #pragma unroll
            for (int r4 = 0; r4 < 4; r4++) {
                float v = deadrow ? -INFINITY : fast_mish(acc[mt][nt][r4]);
                pk |= (unsigned long long)f2bf(v) << (16 * r4);
            }
            int byte = ((((lrow * 128 + col) << 6) + co0) << 1);
            byte ^= (col & 7) << 4;
            *reinterpret_cast<unsigned long long*>(smem + byte) = pk;
        }
    }
    __syncthreads();

    // ---- pool 3x3 s2 over LDS tile + scatter ----
    const int pbase = (n << 12) + ((pr << 1) << 6);
    for (int i = tid; i < 8192; i += 640) {
        int pp = i >> 12;          // 0/1 -> pooled row 2pr+pp
        int c  = (i >> 6) & 63;    // pooled col
        int co = i & 63;
        float m = -INFINITY;
        #pragma unroll
        for (int dy = 0; dy < 3; dy++) {
            int lr = 2 * pp + dy;
            #pragma unroll
            for (int dx = 0; dx < 3; dx++) {
                int x = 2 * c - 1 + dx;
                if (x < 0 || x > 127) continue;
                int byte = ((((lr * 128 + x) << 6) + co) << 1) ^ ((x & 7) << 4);
                unsigned short hv = *reinterpret_cast<const unsigned short*>(smem + byte);
                m = fmaxf(m, __uint_as_float((unsigned)hv << 16));
            }
        }
        int lin = lin_pt[pbase + (pp << 6) + c];
        if (lin >= 0)
            atomicAdd(out + (size_t)(lin >> 15) * 2097152 + (size_t)co * 32768 + (lin & 32767), m);
    }
}

// ---------------- launcher ----------------
extern "C" void kernel_launch(void* const* d_in, const int* in_sizes, int n_in,
                              void* d_out, int out_size, void* d_ws, size_t ws_size,
                              hipStream_t stream)
{
    const float* rgb   = (const float*)d_in[0];
    const float* sxyz  = (const float*)d_in[1];
    const float* w1    = (const float*)d_in[2];
    const float* w2    = (const float*)d_in[3];
    const int*   index = (const int*)d_in[4];
    float* out = (float*)d_out;

    __hip_bfloat16* feat1 = (__hip_bfloat16*)d_ws;
    int* lin_pt = (int*)((char*)d_ws + FEAT1_BYTES);

    hipMemsetAsync(d_out, 0, (size_t)out_size * 4, stream);
    hipMemsetAsync(d_ws, 0, FEAT1_BYTES, stream);   // zeroes feat1 padding too

    point_kernel<<<1024, 256, 0, stream>>>(rgb, sxyz, index, out, lin_pt);
    conv1_mfma_kernel<<<4096, 1024, 0, stream>>>(rgb, w1, feat1);
    conv2_mfma_kernel<<<2048, 640, 0, stream>>>(feat1, w2, lin_pt, out);
}

// Round 8
// 1210.599 us; speedup vs baseline: 5.6994x; 1.3622x over previous
//
#include <hip/hip_runtime.h>
#include <hip/hip_bf16.h>
#include <math.h>

// ---------------- problem constants ----------------
#define N_IMG 64
#define CH    64      // PCN_H
#define F1_R  136     // feat1 padded rows: row y stored at y+4  (used 1..133)
#define F1_C  136     // feat1 padded cols: col x stored at x+4  (used 2..133)
// feat1 channel-last: [n][F1_R][F1_C][64] bf16
#define F1_IMG_STRIDE ((size_t)F1_R * F1_C * 64)
#define F1_ROW_STRIDE (F1_C * 64)
#define FEAT1_BYTES ((size_t)N_IMG * F1_IMG_STRIDE * 2)

// d_out layout (floats):
//   feature_map (8,64,8,64,64)  : [0, 16777216)
//   counts      (8,1,8,64,64)   : [16777216, 17039360)
//   rgb_map     (8,3,8,64,64)   : [17039360, 17825792)
#define OUT_CNT_BASE 16777216
#define OUT_RGB_BASE 17039360

typedef short bf16x8 __attribute__((ext_vector_type(8)));
typedef float f32x4  __attribute__((ext_vector_type(4)));

// mish(x) = x * tanh(softplus(x)) = x * (t^2+2t)/(t^2+2t+2), t=e^x
__device__ __forceinline__ float fast_mish(float x) {
    float xc = fminf(x, 20.0f);
    float t  = __expf(xc);
    float n  = t * (t + 2.0f);
    float y  = x * n / (n + 2.0f);
    return (x > 20.0f) ? x : y;
}

// float -> bf16 bits, round-to-nearest-even (handles +-inf correctly)
__device__ __forceinline__ unsigned short f2bf(float f) {
    unsigned u = __float_as_uint(f);
    unsigned r = (u + 0x7FFFu + ((u >> 16) & 1u)) >> 16;
    return (unsigned short)r;
}

// ------------- kernel 1: per-point binning + rgb/count scatter -------------
__global__ __launch_bounds__(256) void point_kernel(
    const float* __restrict__ rgb,
    const float* __restrict__ sxyz,
    const int*   __restrict__ index,
    float*       __restrict__ out,
    int*         __restrict__ lin_pt)
{
    int p = blockIdx.x * 256 + threadIdx.x;      // 64*64*64 = 262144 points
    int n  = p >> 12;
    int r  = p & 4095;
    int hs = r >> 6;
    int ws = r & 63;

    int row = hs * 4 + 2, col = ws * 4 + 2;
    const float* sx = sxyz + (size_t)n * 3 * 65536;
    float X = sx[row * 256 + col];
    float Y = sx[65536 + row * 256 + col];
    float Z = sx[2 * 65536 + row * 256 + col];

    // replicate JAX op order + trunc-toward-zero int cast
    int hb = (int)(((X + 5.0f) * 64.0f) / 10.0f);
    int wb = (int)(((Y + 5.0f) * 64.0f) / 10.0f);
    int vb = (int)((Z * 8.0f) / 3.0f);
    bool valid = (hb >= 0) & (hb < 64) & (wb >= 0) & (wb < 64) & (vb >= 0) & (vb < 8);

    int b   = index[n];
    int lin = ((b * 8 + vb) * 64 + hb) * 64 + wb;
    lin_pt[p] = valid ? lin : -1;

    if (valid) {
        atomicAdd(out + OUT_CNT_BASE + lin, 1.0f);
        int rem = lin & 32767;
        #pragma unroll
        for (int c = 0; c < 3; c++) {
            const float* rg = rgb + (size_t)(n * 3 + c) * 65536;
            float s = 0.0f;
            #pragma unroll
            for (int i = 0; i < 4; i++)
                #pragma unroll
                for (int j = 0; j < 4; j++)
                    s += rg[(hs * 4 + i) * 256 + (ws * 4 + j)];
            atomicAdd(out + OUT_RGB_BASE + b * 98304 + c * 32768 + rem, s * 0.0625f);
        }
    }
}

// ------------- kernel 2: conv1 via MFMA + mish + maxpool3s2 -> feat1 (channel-last) ----------
// GEMM view: M=64 co, K=32 (3ci x 9taps pad), N=spatial.
// block = (n, pr): pre-pool rows 4pr-1..4pr+3 (5 rows x 256 cols), pools rows 2pr,2pr+1.
// 16 waves x 5 (row,col-tile) tasks x 4 m-tiles; single K-step MFMA.
__global__ __launch_bounds__(1024) void conv1_mfma_kernel(
    const float* __restrict__ rgb,
    const float* __restrict__ w1,
    __hip_bfloat16* __restrict__ feat1)
{
    int b2 = ((blockIdx.x & 7) << 9) + (blockIdx.x >> 3);   // XCD-chunked swizzle (4096 = 8x512)
    const int n  = b2 >> 6;
    const int pr = b2 & 63;
    const int tid  = threadIdx.x;
    const int lane = tid & 63;
    const int w    = tid >> 6;       // 0..15

    __shared__ __align__(16) char smem[81920];
    // MFMA phase: wlds [64co][32k] bf16 @0 (4KB); in_t [3ci][9r][264c]+16 zeros @4096 (14.3KB)
    // epilogue : pool tile [5][256][32co] bf16 @0 (80KB)
    unsigned short* wlds = (unsigned short*)smem;
    unsigned short* in_t = (unsigned short*)(smem + 4096);

    // ---- stage weights [co][k], k = ci*9 + ky*3 + kx (k>=27 -> 0)
    for (int i = tid; i < 2048; i += 1024) {
        int co = i >> 5, k = i & 31;
        wlds[i] = (k < 27) ? f2bf(w1[co * 27 + k]) : (unsigned short)0;
    }
    // ---- stage input tile: rows 4pr-3..4pr+5, cols -2..261, bf16; tail 16 zeros
    {
        const float* img = rgb + (size_t)n * 3 * 65536;
        for (int i = tid; i < 7144; i += 1024) {
            unsigned short v = 0;
            if (i < 7128) {
                int ci  = i / 2376;
                int rem = i - ci * 2376;
                int rr  = rem / 264;
                int cc  = rem - rr * 264;
                int gy  = 4 * pr - 3 + rr;
                int gx  = cc - 2;
                if (gy >= 0 && gy < 256 && gx >= 0 && gx < 256)
                    v = f2bf(img[ci * 65536 + gy * 256 + gx]);
            }
            in_t[i] = v;
        }
    }
    __syncthreads();

    // ---- per-lane B gather offsets (bytes) for k = (lane>>4)*8 + j
    int boff[8];
    #pragma unroll
    for (int j = 0; j < 8; j++) {
        int k = ((lane >> 4) << 3) + j;
        if (k < 27) {
            int ci = k / 9, t = k - 9 * ci, ky = t / 3, kx = t - 3 * ky;
            boff[j] = (ci * 2376 + 2 * ky * 264 + 2 * kx + (lane & 15)) * 2;
        } else {
            boff[j] = 7128 * 2;     // zero slot
        }
    }

    // ---- A fragments (weights), k-map identical to B: k = (lane>>4)*8 + j
    bf16x8 a[4];
    #pragma unroll
    for (int mt = 0; mt < 4; mt++)
        a[mt] = *reinterpret_cast<const bf16x8*>(
            wlds + (mt * 16 + (lane & 15)) * 32 + ((lane >> 4) << 3));

    f32x4 acc[5][4];
    #pragma unroll
    for (int tt = 0; tt < 5; tt++)
        #pragma unroll
        for (int mt = 0; mt < 4; mt++)
            acc[tt][mt] = (f32x4){0.f, 0.f, 0.f, 0.f};

    const char* in_b = (const char*)in_t;
    #pragma unroll
    for (int tt = 0; tt < 5; tt++) {
        int t5 = w * 5 + tt;             // 0..79: 5 rows x 16 col-tiles
        int r  = t5 >> 4;
        int x0 = (t5 & 15) << 4;
        int base = (r * 264 + x0) * 2;
        unsigned short e[8];
        #pragma unroll
        for (int j = 0; j < 8; j++)
            e[j] = *reinterpret_cast<const unsigned short*>(in_b + base + boff[j]);
        bf16x8 b;
        #pragma unroll
        for (int j = 0; j < 8; j++) b[j] = (short)e[j];
        #pragma unroll
        for (int mt = 0; mt < 4; mt++)
            acc[tt][mt] = __builtin_amdgcn_mfma_f32_16x16x32_bf16(a[mt], b, acc[tt][mt], 0, 0, 0);
    }

    __syncthreads();   // wlds/in_t dead; reuse LDS as pool tile

    unsigned short* pool = (unsigned short*)smem;
    const int ybase = 4 * pr - 1;

    // NOTE: fully unrolled so every acc[][] index is compile-time (rule #20:
    // runtime 'p' in mt=p*2+m2 previously sent acc to scratch -> 1.4GB spill traffic)
    #pragma unroll
    for (int p = 0; p < 2; p++) {       // co half
        // write mish'd pre-pool values for co in [p*32, p*32+32)
        #pragma unroll
        for (int tt = 0; tt < 5; tt++) {
            int t5 = w * 5 + tt;
            int r  = t5 >> 4;
            int x  = ((t5 & 15) << 4) + (lane & 15);
            bool dead = (ybase + r) < 0;      // y=-1 pad row -> -inf
            #pragma unroll
            for (int m2 = 0; m2 < 2; m2++) {
                int mt  = p * 2 + m2;
                int col = m2 * 16 + ((lane >> 4) << 2);   // co & 31 (4-aligned)
                unsigned long long pk = 0;
                #pragma unroll
                for (int q = 0; q < 4; q++) {
                    float v = dead ? -INFINITY : fast_mish(acc[tt][mt][q]);
                    pk |= (unsigned long long)f2bf(v) << (16 * q);
                }
                int byte = (((r * 256 + x) * 32) + col) * 2;
                byte ^= (x & 7) << 4;
                *reinterpret_cast<unsigned long long*>((char*)pool + byte) = pk;
            }
        }
        __syncthreads();
        // 3x3 s2 pool + channel-last feat1 store for this co half
        for (int i = tid; i < 8192; i += 1024) {
            int pp = i >> 12;            // pooled row 2pr+pp
            int c  = (i >> 5) & 127;     // pooled col
            int cl = i & 31;
            float m = -INFINITY;
            #pragma unroll
            for (int dy = 0; dy < 3; dy++) {
                int lr = 2 * pp + dy;
                #pragma unroll
                for (int dx = 0; dx < 3; dx++) {
                    int x = 2 * c - 1 + dx;
                    if (x < 0) continue;                  // x<=255 always
                    int byte = ((((lr * 256) + x) * 32) + cl) * 2;
                    byte ^= (x & 7) << 4;
                    unsigned short hv = *reinterpret_cast<const unsigned short*>((char*)pool + byte);
                    m = fmaxf(m, __uint_as_float((unsigned)hv << 16));
                }
            }
            unsigned short* dst = (unsigned short*)(feat1 + (size_t)n * F1_IMG_STRIDE
                + (size_t)(2 * pr + pp + 4) * F1_ROW_STRIDE + (size_t)(c + 4) * 64 + p * 32 + cl);
            *dst = f2bf(m);
        }
        __syncthreads();
    }
}

// ------------- kernel 3: conv2 via MFMA + mish + maxpool3s2 + feature scatter -------------
// block = (n, pr): computes pre-pool rows 4pr-1 .. 4pr+3 (5 rows x 128 cols x 64 co),
// pools rows 2pr, 2pr+1 in LDS, scatters. 10 waves: wave w -> row (w>>1), col-half (w&1).
__global__ __launch_bounds__(640, 3) void conv2_mfma_kernel(
    const __hip_bfloat16* __restrict__ feat1,
    const float* __restrict__ w2,
    const int*   __restrict__ lin_pt,
    float*       __restrict__ out)
{
    // XCD-chunked swizzle: 2048 blocks -> each XCD gets 8 whole images (L2 reuse)
    int b2 = ((blockIdx.x & 7) << 8) + (blockIdx.x >> 3);
    const int n  = b2 >> 5;
    const int pr = b2 & 31;
    const int tid  = threadIdx.x;
    const int lane = tid & 63;
    const int w    = tid >> 6;        // 0..9
    const int lrow = w >> 1;          // local pre-pool row 0..4
    const int chalf = w & 1;          // col half
    const int y = 4 * pr - 1 + lrow;  // global pre-pool row (-1..127)

    __shared__ __align__(16) char smem[81920];   // weights (73728B) then pool tile (81920B)

    // ---- stage W2 -> LDS bf16, layout [tap][co][ci], XOR-swizzled (T2) ----
    for (int i = tid; i < 36864; i += 640) {
        int t  = i >> 12;           // 0..8
        int co = (i >> 6) & 63;
        int ci = i & 63;
        unsigned short h = f2bf(w2[(co * 64 + ci) * 9 + t]);
        int byte = ((((t << 6) + co) << 6) + ci) << 1;
        byte ^= (co & 7) << 4;
        *reinterpret_cast<unsigned short*>(smem + byte) = h;
    }
    __syncthreads();

    f32x4 acc[4][4];
    #pragma unroll
    for (int mt = 0; mt < 4; mt++)
        #pragma unroll
        for (int nt = 0; nt < 4; nt++)
            acc[mt][nt] = (f32x4){0.f, 0.f, 0.f, 0.f};

    // B lane base: row (y-2)+4 = y+2, col (lane&15) + chalf*64 + (-2) + 4
    const __hip_bfloat16* bbase = feat1 + (size_t)n * F1_IMG_STRIDE
        + ((size_t)(y + 2) * F1_C + (lane & 15) + chalf * 64 + 2) * 64
        + ((lane >> 4) << 3);

    #pragma unroll
    for (int ky = 0; ky < 3; ky++) {
        #pragma unroll
        for (int kx = 0; kx < 3; kx++) {
            const int t = ky * 3 + kx;
            #pragma unroll
            for (int s = 0; s < 2; s++) {
                bf16x8 a[4];
                #pragma unroll
                for (int mt = 0; mt < 4; mt++) {
                    int co = mt * 16 + (lane & 15);
                    int byte = ((((t << 6) + co) << 6) + (s << 5) + ((lane >> 4) << 3)) << 1;
                    byte ^= (co & 7) << 4;
                    a[mt] = *reinterpret_cast<const bf16x8*>(smem + byte);
                }
                const __hip_bfloat16* bp = bbase + (ky * 2 * F1_C + kx * 2) * 64 + s * 32;
                #pragma unroll
                for (int nt = 0; nt < 4; nt++) {
                    bf16x8 b = *reinterpret_cast<const bf16x8*>(bp + nt * 1024);
                    #pragma unroll
                    for (int mt = 0; mt < 4; mt++)
                        acc[mt][nt] = __builtin_amdgcn_mfma_f32_16x16x32_bf16(
                            a[mt], b, acc[mt][nt], 0, 0, 0);
                }
            }
        }
    }

    __syncthreads();   // weights region now dead; reuse LDS for pool tile

    // ---- epilogue: mish -> bf16 -> pool tile LDS [5][128][64], XOR ((col&7)<<4) ----
    const bool deadrow = (y < 0);   // maxpool padding row = -inf
    #pragma unroll
    for (int nt = 0; nt < 4; nt++) {
        int col = chalf * 64 + nt * 16 + (lane & 15);
        #pragma unroll
        for (int mt = 0; mt < 4; mt++) {
            int co0 = mt * 16 + ((lane >> 4) << 2);
            unsigned long long pk = 0;
            #pragma unroll
            for (int r4 = 0; r4 < 4; r4++) {
                float v = deadrow ? -INFINITY : fast_mish(acc[mt][nt][r4]);
                pk |= (unsigned long long)f2bf(v) << (16 * r4);
            }
            int byte = ((((lrow * 128 + col) << 6) + co0) << 1);
            byte ^= (col & 7) << 4;
            *reinterpret_cast<unsigned long long*>(smem + byte) = pk;
        }
    }
    __syncthreads();

    // ---- pool 3x3 s2 over LDS tile + scatter ----
    const int pbase = (n << 12) + ((pr << 1) << 6);
    for (int i = tid; i < 8192; i += 640) {
        int pp = i >> 12;          // 0/1 -> pooled row 2pr+pp
        int c  = (i >> 6) & 63;    // pooled col
        int co = i & 63;
        float m = -INFINITY;
        #pragma unroll
        for (int dy = 0; dy < 3; dy++) {
            int lr = 2 * pp + dy;
            #pragma unroll
            for (int dx = 0; dx < 3; dx++) {
                int x = 2 * c - 1 + dx;
                if (x < 0 || x > 127) continue;
                int byte = ((((lr * 128 + x) << 6) + co) << 1) ^ ((x & 7) << 4);
                unsigned short hv = *reinterpret_cast<const unsigned short*>(smem + byte);
                m = fmaxf(m, __uint_as_float((unsigned)hv << 16));
            }
        }
        int lin = lin_pt[pbase + (pp << 6) + c];
        if (lin >= 0)
            atomicAdd(out + (size_t)(lin >> 15) * 2097152 + (size_t)co * 32768 + (lin & 32767), m);
    }
}

// ---------------- launcher ----------------
extern "C" void kernel_launch(void* const* d_in, const int* in_sizes, int n_in,
                              void* d_out, int out_size, void* d_ws, size_t ws_size,
                              hipStream_t stream)
{
    const float* rgb   = (const float*)d_in[0];
    const float* sxyz  = (const float*)d_in[1];
    const float* w1    = (const float*)d_in[2];
    const float* w2    = (const float*)d_in[3];
    const int*   index = (const int*)d_in[4];
    float* out = (float*)d_out;

    __hip_bfloat16* feat1 = (__hip_bfloat16*)d_ws;
    int* lin_pt = (int*)((char*)d_ws + FEAT1_BYTES);

    hipMemsetAsync(d_out, 0, (size_t)out_size * 4, stream);
    hipMemsetAsync(d_ws, 0, FEAT1_BYTES, stream);   // zeroes feat1 padding too

    point_kernel<<<1024, 256, 0, stream>>>(rgb, sxyz, index, out, lin_pt);
    conv1_mfma_kernel<<<4096, 1024, 0, stream>>>(rgb, w1, feat1);
    conv2_mfma_kernel<<<2048, 640, 0, stream>>>(feat1, w2, lin_pt, out);
}